// Round 8
// baseline (327.950 us; speedup 1.0000x reference)
//
#include <hip/hip_runtime.h>

#define HH   224
#define WW   224
#define HW_  (HH * WW)
#define TS   16
#define HL   18               // halo dim (16 + 2)
#define NPIX (HL * HL)        // 324
#define XROW 136              // bytes per pixel: 64ch*2B = 128 + 8 pad (34 dwords, kills 32-bank alias)

typedef __attribute__((ext_vector_type(8))) short bf16x8;
typedef __attribute__((ext_vector_type(4))) short bf16x4;
typedef __attribute__((ext_vector_type(4))) float f32x4;

static __device__ __forceinline__ unsigned short f2bf(float f) {
    unsigned u = __float_as_uint(f);
    u += 0x7FFFu + ((u >> 16) & 1u);          // RNE
    return (unsigned short)(u >> 16);
}
static __device__ __forceinline__ float bf2f(unsigned short h) {
    return __uint_as_float(((unsigned)h) << 16);
}

// ---- pre-kernel: w1 -> bf16 [64 o][64 c]; w2 -> bf16 reordered [9 tap][64 ch][64 o] ----
__global__ __launch_bounds__(256) void prep_weights(
    const float* __restrict__ w1, const float* __restrict__ w2,
    unsigned short* __restrict__ wsb)
{
    const int j = blockIdx.x * 256 + threadIdx.x;   // 0..36863
    unsigned short* w1b = wsb;                      // 4096 bf16
    unsigned short* w2r = wsb + 4096;               // 36864 bf16: [t][c][o]
    if (j < 4096) w1b[j] = f2bf(w1[j]);
    if (j < 36864) {
        const int t = j >> 12;
        const int c = (j >> 6) & 63;
        const int o = j & 63;
        w2r[j] = f2bf(w2[(c * 9 + t) * 64 + o]);
    }
}

// LDS: pixel-major xs only: 324 pix x 136B = 44,064 B -> 3 blocks/CU
__global__ __launch_bounds__(256, 3) void dynconv_tapacc(
    const float* __restrict__ x, const unsigned short* __restrict__ wsb,
    float* __restrict__ out)
{
    __shared__ __align__(16) unsigned char xsb[NPIX * XROW];

    const unsigned char* w1b  = (const unsigned char*)wsb;            // bf16 [64 o][64 c]
    const unsigned char* w2rp = (const unsigned char*)(wsb + 4096);   // bf16 [9 t][64 c][64 o]

    const int b    = blockIdx.z;
    const int ty0  = blockIdx.y * TS;
    const int tx0  = blockIdx.x * TS;
    const int tid  = threadIdx.x;
    const int lane = tid & 63;
    const int w    = tid >> 6;      // wave 0..3 -> pixel rows w*4..w*4+3
    const int tx   = lane & 15;
    const int g    = lane >> 4;

    const float* xb = x + (size_t)b * 64 * HW_;

    // ---- stage x halo tile (fp32 -> bf16), pixel-major, channel pairs ----
    for (int i = tid; i < 32 * NPIX; i += 256) {
        int cp  = i / NPIX;          // channel pair 0..31
        int pix = i - cp * NPIX;
        int r   = pix / HL;
        int col = pix - r * HL;
        int gy  = ty0 + r - 1;
        int gx  = tx0 + col - 1;
        float f0 = 0.f, f1 = 0.f;
        if ((unsigned)gy < (unsigned)HH && (unsigned)gx < (unsigned)WW) {
            const float* p = xb + (size_t)(2 * cp) * HW_ + gy * WW + gx;
            f0 = p[0];
            f1 = p[HW_];
        }
        unsigned pk = (unsigned)f2bf(f0) | ((unsigned)f2bf(f1) << 16);
        *(unsigned*)(xsb + pix * XROW + cp * 4) = pk;
    }
    __syncthreads();

    // ---- GEMM1: h = relu(w1 . x) via 16x16x32; packed directly into GEMM2
    //      B-fragments bq[q][kb] (16x16x16 B layout k=4g+j == C/D row=4g+r) ----
    bf16x4 bq[4][4];
    {
        bf16x8 aw1[4][2];
        #pragma unroll
        for (int mt = 0; mt < 4; ++mt)
            #pragma unroll
            for (int kt = 0; kt < 2; ++kt)
                aw1[mt][kt] = *(const bf16x8*)(w1b + (mt * 16 + tx) * 128 + kt * 64 + g * 16);
        #pragma unroll
        for (int q = 0; q < 4; ++q) {
            const int center = (w * 4 + q + 1) * HL + (tx + 1);
            bf16x8 bx0 = *(const bf16x8*)(xsb + center * XROW + g * 16);        // c = g*8..+7
            bf16x8 bx1 = *(const bf16x8*)(xsb + center * XROW + 64 + g * 16);   // c = 32+g*8..
            #pragma unroll
            for (int mt = 0; mt < 4; ++mt) {
                f32x4 hc = {0.f, 0.f, 0.f, 0.f};
                hc = __builtin_amdgcn_mfma_f32_16x16x32_bf16(aw1[mt][0], bx0, hc, 0, 0, 0);
                hc = __builtin_amdgcn_mfma_f32_16x16x32_bf16(aw1[mt][1], bx1, hc, 0, 0, 0);
                unsigned lo = (unsigned)f2bf(fmaxf(hc[0], 0.f)) | ((unsigned)f2bf(fmaxf(hc[1], 0.f)) << 16);
                unsigned hi = (unsigned)f2bf(fmaxf(hc[2], 0.f)) | ((unsigned)f2bf(fmaxf(hc[3], 0.f)) << 16);
                union { uint2 u; bf16x4 v; } cv;
                cv.u = make_uint2(lo, hi);
                bq[q][mt] = cv.v;    // h[o = mt*16 + 4g + j][pix(q,tx)]
            }
        }
    }

    // ---- GEMM2 restructured: M = 16 channels per tile (4 tiles), loop 9 taps;
    //      kern[t][c][pix] folded into out_acc across taps -> no shfl, no pad ----
    f32x4 out_acc[4][4];   // [q][m]: c = m*16 + 4g + r, pixel (row w*4+q, col tx)
    #pragma unroll
    for (int q = 0; q < 4; ++q)
        #pragma unroll
        for (int m = 0; m < 4; ++m)
            out_acc[q][m] = f32x4{0.f, 0.f, 0.f, 0.f};

    const unsigned char* w2l = w2rp + tx * 128 + g * 8;   // + t*8192 + m*2048 + kb*32

    #pragma unroll
    for (int t = 0; t < 9; ++t) {
        const int dy = t / 3, dx = t - dy * 3;            // compile-time (t unrolled)

        // A-fragments for this tap: 16 x uint2 (4 m-tiles x 4 kb)
        union { uint2 u; bf16x4 v; } af[4][4];
        #pragma unroll
        for (int m = 0; m < 4; ++m)
            #pragma unroll
            for (int kb = 0; kb < 4; ++kb)
                af[m][kb].u = *(const uint2*)(w2l + t * 8192 + m * 2048 + kb * 32);

        // patch byte offsets per q (shifted pixel, this lane's 4 channels at m*32+g*8)
        int pby[4];
        #pragma unroll
        for (int q = 0; q < 4; ++q)
            pby[q] = ((w * 4 + q + dy) * HL + (tx + dx)) * XROW + g * 8;

        #pragma unroll
        for (int m = 0; m < 4; ++m) {
            #pragma unroll
            for (int q = 0; q < 4; ++q) {
                ushort4 pv = *(const ushort4*)(xsb + pby[q] + m * 32);
                f32x4 kern = {0.f, 0.f, 0.f, 0.f};
                #pragma unroll
                for (int kb = 0; kb < 4; ++kb)
                    kern = __builtin_amdgcn_mfma_f32_16x16x16bf16_1k(af[m][kb].v, bq[q][kb], kern, 0, 0, 0);
                out_acc[q][m][0] = fmaf(kern[0], bf2f(pv.x), out_acc[q][m][0]);
                out_acc[q][m][1] = fmaf(kern[1], bf2f(pv.y), out_acc[q][m][1]);
                out_acc[q][m][2] = fmaf(kern[2], bf2f(pv.z), out_acc[q][m][2]);
                out_acc[q][m][3] = fmaf(kern[3], bf2f(pv.w), out_acc[q][m][3]);
            }
        }
    }

    // ---- store: lane covers 4q x 4m x 4r = 64 outputs; 16-lane rows contiguous ----
    float* ob = out + (size_t)b * 64 * HW_ + (size_t)(ty0 + w * 4) * WW + tx0 + tx;
    #pragma unroll
    for (int m = 0; m < 4; ++m)
        #pragma unroll
        for (int q = 0; q < 4; ++q)
            #pragma unroll
            for (int r = 0; r < 4; ++r)
                ob[(size_t)(m * 16 + 4 * g + r) * HW_ + q * WW] = out_acc[q][m][r];
}

extern "C" void kernel_launch(void* const* d_in, const int* in_sizes, int n_in,
                              void* d_out, int out_size, void* d_ws, size_t ws_size,
                              hipStream_t stream) {
    (void)in_sizes; (void)n_in; (void)out_size; (void)ws_size;
    const float* x  = (const float*)d_in[0];
    const float* w1 = (const float*)d_in[1];
    const float* w2 = (const float*)d_in[2];
    float* out = (float*)d_out;
    unsigned short* wsb = (unsigned short*)d_ws;    // 81,920 bytes used

    prep_weights<<<144, 256, 0, stream>>>(w1, w2, wsb);

    dim3 grid(WW / TS, HH / TS, 4);   // 14 x 14 x 4 = 784
    dynconv_tapacc<<<grid, 256, 0, stream>>>(x, wsb, out);
}